// Round 1
// baseline (396.267 us; speedup 1.0000x reference)
//
#include <hip/hip_runtime.h>
#include <hip/hip_bf16.h>

#define N   20000
#define E   320000
#define H   64
#define EA  9
#define EPS 1e-5f

#define TILE 64
#define SVS  68   // LDS row stride in floats (272 B: 16B-aligned rows)

// workspace element offsets (all 16-element aligned where needed)
#define OFF_DEG    0
#define OFF_ATTR   (N)                       // N*EA floats (contiguous w/ deg for one memset)
#define OFF_ROWPTR (N + N*EA)                // 200000
#define OFF_CURSOR 220016
#define OFF_PK     240032                    // E int2
#define OFF_H0     880032
#define OFF_H1     2160032
// total = 3440032 elems = 13.76 MB

__global__ void k_count(const int* __restrict__ ei, const float* __restrict__ eattr,
                        int* __restrict__ deg, float* __restrict__ attr) {
    int t = blockIdx.x * 256 + threadIdx.x;
    int e = t >> 4, q = t & 15;
    if (e >= E) return;
    int s = ei[e];
    if (q < EA)       atomicAdd(&attr[s * EA + q], eattr[e * EA + q]);
    else if (q == EA) atomicAdd(&deg[s], 1);
}

__global__ void k_scan(const int* __restrict__ deg, int* __restrict__ rowptr,
                       int* __restrict__ cursor) {
    __shared__ int wsum[16];
    __shared__ int carry;
    const int tid = threadIdx.x, lane = tid & 63, w = tid >> 6;
    if (tid == 0) carry = 0;
    __syncthreads();
    for (int base = 0; base < N; base += 1024) {
        int i = base + tid;
        int v = (i < N) ? deg[i] : 0;
        int s = v;
        #pragma unroll
        for (int off = 1; off < 64; off <<= 1) {
            int t = __shfl_up(s, off);
            if (lane >= off) s += t;
        }
        if (lane == 63) wsum[w] = s;
        __syncthreads();
        if (w == 0 && lane < 16) {
            int t = wsum[lane];
            #pragma unroll
            for (int off = 1; off < 16; off <<= 1) {
                int u = __shfl_up(t, off);
                if (lane >= off) t += u;
            }
            wsum[lane] = t;
        }
        __syncthreads();
        int waveoff = (w == 0) ? 0 : wsum[w - 1];
        int excl = carry + waveoff + s - v;
        if (i < N) { rowptr[i] = excl; cursor[i] = excl; }
        __syncthreads();
        if (tid == 0) carry += wsum[15];
        __syncthreads();
    }
    if (threadIdx.x == 0) rowptr[N] = carry;
}

__global__ void k_fill(const int* __restrict__ ei, int* __restrict__ cursor,
                       int2* __restrict__ pk) {
    int e = blockIdx.x * 256 + threadIdx.x;
    if (e >= E) return;
    int s = ei[e], d = ei[E + e];
    int p = atomicAdd(&cursor[s], 1);
    pk[p] = make_int2(d, s);
}

__global__ void k_h0(const int* __restrict__ x, const float* __restrict__ emb0,
                     float* __restrict__ h0) {
    int t = blockIdx.x * 256 + threadIdx.x;
    if (t >= N * H) return;
    int i = t >> 6, l = t & 63;
    h0[t] = emb0[x[i] * H + l];
}

#define PROC(ss, vv) { int s_ = (ss); float v_ = (vv);                              \
    if (s_ != runsrc) {                                                             \
        if (runsrc >= 0) atomicAdd(&sB[lane * SVS + (runsrc - n0)], runval);        \
        runsrc = s_; runval = v_;                                                   \
    } else runval += v_; }

__global__ __launch_bounds__(256, 4) void k_layer(
        const float* __restrict__ h_in, float* __restrict__ h_out,
        const int* __restrict__ rowptr, const int2* __restrict__ pk,
        const float* __restrict__ attr,
        const float* __restrict__ WeL, const float* __restrict__ beL,
        const float* __restrict__ W1L, const float* __restrict__ b1L,
        const float* __restrict__ gammaL, const float* __restrict__ betaL,
        const float* __restrict__ meanL, const float* __restrict__ varL,
        const float* __restrict__ W2L, const float* __restrict__ b2L,
        const int* __restrict__ slip, const int* __restrict__ sltp,
        int relu_out) {
    __shared__ float sB[128 * SVS];          // 34816 B, V tile then z1r tile
    const int tid = threadIdx.x;
    const int wave = tid >> 6, lane = tid & 63;
    const int n0 = blockIdx.x * TILE;

    const int   slidx = slip[0];
    const float slt   = (float)sltp[0];

    // ---- Phase A0: self-loop / bias / edge-attr init of V tile ----
    #pragma unroll
    for (int i = 0; i < 16; ++i) {
        int r = wave * 16 + i;
        int n = n0 + r;
        float aH = 0.f, aE = 0.f;
        if (n < N) {
            aH = h_in[n * H + lane];
            int dcnt = rowptr[n + 1] - rowptr[n];
            aE = slt * WeL[slidx * H + lane] + (float)(dcnt + 1) * beL[lane];
            #pragma unroll
            for (int j = 0; j < EA; ++j) aE += attr[n * EA + j] * WeL[j * H + lane];
        }
        sB[lane * SVS + r]       = aH;
        sB[(H + lane) * SVS + r] = aE;
    }
    __syncthreads();

    // ---- Phase A1: CSR edge gather (run-merged, LDS-atomic flush) ----
    {
        int p0 = rowptr[n0];
        int p1 = rowptr[min(n0 + TILE, N)];
        int total = p1 - p0;
        int per = (total + 3) >> 2;
        int p  = p0 + wave * per;
        int pe = min(p + per, p1);
        int runsrc = -1;
        float runval = 0.f;
        for (; p + 4 <= pe; p += 4) {
            int2 e0 = pk[p], e1 = pk[p + 1], e2 = pk[p + 2], e3 = pk[p + 3];
            float v0 = h_in[e0.x * H + lane];
            float v1 = h_in[e1.x * H + lane];
            float v2 = h_in[e2.x * H + lane];
            float v3 = h_in[e3.x * H + lane];
            PROC(e0.y, v0) PROC(e1.y, v1) PROC(e2.y, v2) PROC(e3.y, v3)
        }
        for (; p < pe; ++p) {
            int2 e0 = pk[p];
            float v0 = h_in[e0.x * H + lane];
            PROC(e0.y, v0)
        }
        if (runsrc >= 0) atomicAdd(&sB[lane * SVS + (runsrc - n0)], runval);
    }
    __syncthreads();

    // ---- Phase B: z1 = V @ W1, 8x4 micro-tile per thread ----
    float acc[8][4];
    {
        const int tc = tid & 31, tr = tid >> 5;
        #pragma unroll
        for (int i = 0; i < 8; ++i)
            #pragma unroll
            for (int j = 0; j < 4; ++j) acc[i][j] = 0.f;
        const float* wp = W1L + tc * 4;
        #pragma unroll 4
        for (int k = 0; k < 128; ++k) {
            float4 w  = *(const float4*)(wp + k * 128);
            float4 va = *(const float4*)(&sB[k * SVS + tr * 8]);
            float4 vb = *(const float4*)(&sB[k * SVS + tr * 8 + 4]);
            float wr[4] = {w.x, w.y, w.z, w.w};
            float vr[8] = {va.x, va.y, va.z, va.w, vb.x, vb.y, vb.z, vb.w};
            #pragma unroll
            for (int i = 0; i < 8; ++i)
                #pragma unroll
                for (int j = 0; j < 4; ++j) acc[i][j] += vr[i] * wr[j];
        }
    }
    __syncthreads();   // V tile fully consumed; sB reused for z1r

    // ---- BN (folded b1) + ReLU -> sB as z1r[k][r] ----
    {
        const int tc = tid & 31, tr = tid >> 5;
        const int c0 = tc * 4;
        float4 g  = *(const float4*)(gammaL + c0);
        float4 bt = *(const float4*)(betaL + c0);
        float4 mn = *(const float4*)(meanL + c0);
        float4 vv = *(const float4*)(varL + c0);
        float4 bb = *(const float4*)(b1L + c0);
        float sc[4], sh[4];
        sc[0] = g.x * rsqrtf(vv.x + EPS); sh[0] = (bb.x - mn.x) * sc[0] + bt.x;
        sc[1] = g.y * rsqrtf(vv.y + EPS); sh[1] = (bb.y - mn.y) * sc[1] + bt.y;
        sc[2] = g.z * rsqrtf(vv.z + EPS); sh[2] = (bb.z - mn.z) * sc[2] + bt.z;
        sc[3] = g.w * rsqrtf(vv.w + EPS); sh[3] = (bb.w - mn.w) * sc[3] + bt.w;
        #pragma unroll
        for (int j = 0; j < 4; ++j)
            #pragma unroll
            for (int i = 0; i < 8; ++i) {
                float z = fmaxf(acc[i][j] * sc[j] + sh[j], 0.f);
                sB[(c0 + j) * SVS + tr * 8 + i] = z;
            }
    }
    __syncthreads();

    // ---- Phase C: z2 = z1r @ W2 (+b2, +relu), 4x4 micro-tile ----
    {
        const int tc = tid & 15, tr = tid >> 4;
        float a2[4][4];
        #pragma unroll
        for (int i = 0; i < 4; ++i)
            #pragma unroll
            for (int j = 0; j < 4; ++j) a2[i][j] = 0.f;
        const float* wp = W2L + tc * 4;
        #pragma unroll 4
        for (int k = 0; k < 128; ++k) {
            float4 w = *(const float4*)(wp + k * 64);
            float4 v = *(const float4*)(&sB[k * SVS + tr * 4]);
            float wr[4] = {w.x, w.y, w.z, w.w};
            float vr[4] = {v.x, v.y, v.z, v.w};
            #pragma unroll
            for (int i = 0; i < 4; ++i)
                #pragma unroll
                for (int j = 0; j < 4; ++j) a2[i][j] += vr[i] * wr[j];
        }
        const int c0 = tc * 4;
        float4 b2v = *(const float4*)(b2L + c0);
        #pragma unroll
        for (int i = 0; i < 4; ++i) {
            int n = n0 + tr * 4 + i;
            if (n < N) {
                float4 o;
                o.x = a2[i][0] + b2v.x;
                o.y = a2[i][1] + b2v.y;
                o.z = a2[i][2] + b2v.z;
                o.w = a2[i][3] + b2v.w;
                if (relu_out) {
                    o.x = fmaxf(o.x, 0.f); o.y = fmaxf(o.y, 0.f);
                    o.z = fmaxf(o.z, 0.f); o.w = fmaxf(o.w, 0.f);
                }
                *(float4*)(h_out + n * H + c0) = o;
            }
        }
    }
}
#undef PROC

extern "C" void kernel_launch(void* const* d_in, const int* in_sizes, int n_in,
                              void* d_out, int out_size, void* d_ws, size_t ws_size,
                              hipStream_t stream) {
    const int*   x     = (const int*)d_in[0];
    const int*   ei    = (const int*)d_in[1];
    const float* eattr = (const float*)d_in[2];
    const float* emb0  = (const float*)d_in[3];
    const float* We    = (const float*)d_in[4];
    const float* be    = (const float*)d_in[5];
    const float* W1    = (const float*)d_in[6];
    const float* b1    = (const float*)d_in[7];
    const float* gamma = (const float*)d_in[8];
    const float* beta  = (const float*)d_in[9];
    const float* bnm   = (const float*)d_in[10];
    const float* bnv   = (const float*)d_in[11];
    const float* W2    = (const float*)d_in[12];
    const float* b2    = (const float*)d_in[13];
    const int*   slip  = (const int*)d_in[14];
    const int*   sltp  = (const int*)d_in[15];
    float* out = (float*)d_out;

    int*   deg    = (int*)d_ws + OFF_DEG;
    float* attr   = (float*)d_ws + OFF_ATTR;
    int*   rowptr = (int*)d_ws + OFF_ROWPTR;
    int*   cursor = (int*)d_ws + OFF_CURSOR;
    int2*  pk     = (int2*)((int*)d_ws + OFF_PK);
    float* h0     = (float*)d_ws + OFF_H0;
    float* h1     = (float*)d_ws + OFF_H1;

    // zero deg + agg_attr (contiguous)
    hipMemsetAsync(d_ws, 0, (size_t)(N + N * EA) * 4, stream);

    k_count<<<dim3((E * 16 + 255) / 256), dim3(256), 0, stream>>>(ei, eattr, deg, attr);
    k_scan<<<dim3(1), dim3(1024), 0, stream>>>(deg, rowptr, cursor);
    k_fill<<<dim3((E + 255) / 256), dim3(256), 0, stream>>>(ei, cursor, pk);
    k_h0<<<dim3((N * H + 255) / 256), dim3(256), 0, stream>>>(x, emb0, h0);

    const int nblk = (N + TILE - 1) / TILE;
    // layer 0: h0 -> h1
    k_layer<<<dim3(nblk), dim3(256), 0, stream>>>(h0, h1, rowptr, pk, attr,
        We + 0 * EA * H, be + 0 * H, W1 + 0 * 128 * 128, b1 + 0 * 128,
        gamma + 0 * 128, beta + 0 * 128, bnm + 0 * 128, bnv + 0 * 128,
        W2 + 0 * 128 * 64, b2 + 0 * 64, slip, sltp, 1);
    // layer 1: h1 -> h0
    k_layer<<<dim3(nblk), dim3(256), 0, stream>>>(h1, h0, rowptr, pk, attr,
        We + 1 * EA * H, be + 1 * H, W1 + 1 * 128 * 128, b1 + 1 * 128,
        gamma + 1 * 128, beta + 1 * 128, bnm + 1 * 128, bnv + 1 * 128,
        W2 + 1 * 128 * 64, b2 + 1 * 64, slip, sltp, 1);
    // layer 2: h0 -> out (no final relu)
    k_layer<<<dim3(nblk), dim3(256), 0, stream>>>(h0, out, rowptr, pk, attr,
        We + 2 * EA * H, be + 2 * H, W1 + 2 * 128 * 128, b1 + 2 * 128,
        gamma + 2 * 128, beta + 2 * 128, bnm + 2 * 128, bnv + 2 * 128,
        W2 + 2 * 128 * 64, b2 + 2 * 64, slip, sltp, 0);
}

// Round 2
// 309.925 us; speedup vs baseline: 1.2786x; 1.2786x over previous
//
#include <hip/hip_runtime.h>
#include <hip/hip_bf16.h>

#define N   20000
#define E   320000
#define H   64
#define EA  9
#define EPS 1e-5f

#define SV  36     // LDS row stride in floats (144 B = 16B multiple)

// workspace element offsets
#define OFF_DEG    0
#define OFF_ATTR   20000
#define OFF_ROWPTR 200000
#define OFF_CURSOR 220016
#define OFF_PK     240016
#define OFF_H0     560016
#define OFF_H1     1840016
// total 3120016 elems = 12.48 MB

__global__ void k_count(const int* __restrict__ ei, const float* __restrict__ eattr,
                        int* __restrict__ deg, float* __restrict__ attr) {
    int t = blockIdx.x * 256 + threadIdx.x;
    int e = t >> 4, q = t & 15;
    if (e >= E) return;
    int s = ei[e];
    if (q < EA)       atomicAdd(&attr[s * EA + q], eattr[e * EA + q]);
    else if (q == EA) atomicAdd(&deg[s], 1);
}

// single block, 1024 threads, 20 elems/thread, one block-scan
__global__ void k_scan(const int* __restrict__ deg, int* __restrict__ rowptr,
                       int* __restrict__ cursor) {
    __shared__ int wsum[16];
    const int tid = threadIdx.x, lane = tid & 63, w = tid >> 6;
    const int i0 = tid * 20;
    int loc[20];
    int s = 0;
    #pragma unroll
    for (int j = 0; j < 20; ++j) {
        int i = i0 + j;
        int v = (i < N) ? deg[i] : 0;
        loc[j] = v; s += v;
    }
    int t = s;
    #pragma unroll
    for (int off = 1; off < 64; off <<= 1) {
        int u = __shfl_up(t, off);
        if (lane >= off) t += u;
    }
    if (lane == 63) wsum[w] = t;
    __syncthreads();
    if (w == 0 && lane < 16) {
        int u = wsum[lane];
        #pragma unroll
        for (int off = 1; off < 16; off <<= 1) {
            int z = __shfl_up(u, off);
            if (lane >= off) u += z;
        }
        wsum[lane] = u;
    }
    __syncthreads();
    int excl = ((w == 0) ? 0 : wsum[w - 1]) + t - s;
    #pragma unroll
    for (int j = 0; j < 20; ++j) {
        int i = i0 + j;
        if (i < N) { rowptr[i] = excl; cursor[i] = excl; }
        excl += loc[j];
    }
    if (tid == 1023) rowptr[N] = excl;
}

__global__ void k_fill(const int* __restrict__ ei, int* __restrict__ cursor,
                       int* __restrict__ pk) {
    int e = blockIdx.x * 256 + threadIdx.x;
    if (e >= E) return;
    int s = ei[e], d = ei[E + e];
    int p = atomicAdd(&cursor[s], 1);
    pk[p] = d;
}

__global__ void k_h0(const int* __restrict__ x, const float* __restrict__ emb0,
                     float* __restrict__ h0) {
    int t = blockIdx.x * 256 + threadIdx.x;
    if (t >= N * H) return;
    int i = t >> 6, l = t & 63;
    h0[t] = emb0[x[i] * H + l];
}

// one wave per node: gather sum of neighbor h rows (+self) into aggH
__global__ __launch_bounds__(256, 8) void k_gather(
        const float* __restrict__ h_in, float* __restrict__ aggH,
        const int* __restrict__ rowptr, const int* __restrict__ pk) {
    const int lane = threadIdx.x & 63;
    const int n = blockIdx.x * 4 + (threadIdx.x >> 6);
    const int p0 = rowptr[n], p1 = rowptr[n + 1];
    float acc = h_in[n * H + lane];
    int p = p0;
    for (; p + 4 <= p1; p += 4) {
        int d0 = pk[p], d1 = pk[p + 1], d2 = pk[p + 2], d3 = pk[p + 3];
        float v0 = h_in[d0 * H + lane];
        float v1 = h_in[d1 * H + lane];
        float v2 = h_in[d2 * H + lane];
        float v3 = h_in[d3 * H + lane];
        acc += v0; acc += v1; acc += v2; acc += v3;
    }
    for (; p < p1; ++p) acc += h_in[pk[p] * H + lane];
    aggH[n * H + lane] = acc;
}

// 32-row tile MLP: V=[aggH | attr@We + deg*be + selfloop], z1=V@W1, BN, ReLU, z2=z1@W2
// aggH may alias h_out (each block reads only its own rows before writing them)
__global__ __launch_bounds__(256, 4) void k_mlp(
        const float* __restrict__ aggH, float* __restrict__ h_out,
        const int* __restrict__ rowptr, const float* __restrict__ attr,
        const float* __restrict__ WeL, const float* __restrict__ beL,
        const float* __restrict__ W1L, const float* __restrict__ b1L,
        const float* __restrict__ gammaL, const float* __restrict__ betaL,
        const float* __restrict__ meanL, const float* __restrict__ varL,
        const float* __restrict__ W2L, const float* __restrict__ b2L,
        const int* __restrict__ slip, const int* __restrict__ sltp,
        int relu_out) {
    __shared__ float sB[128 * SV];   // 18432 B: V^T tile, then z1r tile
    const int tid = threadIdx.x;
    const int n0 = blockIdx.x * 32;

    // ---- Phase A: build V^T in LDS ----
    {
        const int r = tid >> 3, u = tid & 7;   // r: 0..31 rows, u: 8 col-groups
        const int n = n0 + r;
        // h-part: cols 0..63
        float4 a0 = *(const float4*)(aggH + n * H + u * 8);
        float4 a1 = *(const float4*)(aggH + n * H + u * 8 + 4);
        sB[(u * 8 + 0) * SV + r] = a0.x;
        sB[(u * 8 + 1) * SV + r] = a0.y;
        sB[(u * 8 + 2) * SV + r] = a0.z;
        sB[(u * 8 + 3) * SV + r] = a0.w;
        sB[(u * 8 + 4) * SV + r] = a1.x;
        sB[(u * 8 + 5) * SV + r] = a1.y;
        sB[(u * 8 + 6) * SV + r] = a1.z;
        sB[(u * 8 + 7) * SV + r] = a1.w;
        // e-part: cols 64..127
        const int slidx = slip[0];
        const float slt = (float)sltp[0];
        float dcnt = (float)(rowptr[n + 1] - rowptr[n] + 1);
        float at[EA];
        #pragma unroll
        for (int j = 0; j < EA; ++j) at[j] = attr[n * EA + j];
        float4 v0, v1;
        {
            float4 s0 = *(const float4*)(WeL + slidx * H + u * 8);
            float4 s1 = *(const float4*)(WeL + slidx * H + u * 8 + 4);
            float4 e0 = *(const float4*)(beL + u * 8);
            float4 e1 = *(const float4*)(beL + u * 8 + 4);
            v0.x = slt * s0.x + dcnt * e0.x; v0.y = slt * s0.y + dcnt * e0.y;
            v0.z = slt * s0.z + dcnt * e0.z; v0.w = slt * s0.w + dcnt * e0.w;
            v1.x = slt * s1.x + dcnt * e1.x; v1.y = slt * s1.y + dcnt * e1.y;
            v1.z = slt * s1.z + dcnt * e1.z; v1.w = slt * s1.w + dcnt * e1.w;
        }
        #pragma unroll
        for (int k = 0; k < EA; ++k) {
            float4 w0 = *(const float4*)(WeL + k * H + u * 8);
            float4 w1 = *(const float4*)(WeL + k * H + u * 8 + 4);
            v0.x += at[k] * w0.x; v0.y += at[k] * w0.y;
            v0.z += at[k] * w0.z; v0.w += at[k] * w0.w;
            v1.x += at[k] * w1.x; v1.y += at[k] * w1.y;
            v1.z += at[k] * w1.z; v1.w += at[k] * w1.w;
        }
        sB[(H + u * 8 + 0) * SV + r] = v0.x;
        sB[(H + u * 8 + 1) * SV + r] = v0.y;
        sB[(H + u * 8 + 2) * SV + r] = v0.z;
        sB[(H + u * 8 + 3) * SV + r] = v0.w;
        sB[(H + u * 8 + 4) * SV + r] = v1.x;
        sB[(H + u * 8 + 5) * SV + r] = v1.y;
        sB[(H + u * 8 + 6) * SV + r] = v1.z;
        sB[(H + u * 8 + 7) * SV + r] = v1.w;
    }
    __syncthreads();

    // ---- Phase B: z1 = V @ W1 ; thread = 4 rows x 4 cols ----
    const int tc = tid & 31, tr = tid >> 5;   // tc: col grp 0..31, tr: row grp 0..7
    float acc[4][4];
    #pragma unroll
    for (int i = 0; i < 4; ++i)
        #pragma unroll
        for (int j = 0; j < 4; ++j) acc[i][j] = 0.f;
    {
        const float* wp = W1L + tc * 4;
        #pragma unroll 4
        for (int k = 0; k < 128; ++k) {
            float4 w = *(const float4*)(wp + k * 128);
            float4 v = *(const float4*)(&sB[k * SV + tr * 4]);
            float wr[4] = {w.x, w.y, w.z, w.w};
            float vr[4] = {v.x, v.y, v.z, v.w};
            #pragma unroll
            for (int i = 0; i < 4; ++i)
                #pragma unroll
                for (int j = 0; j < 4; ++j) acc[i][j] += vr[i] * wr[j];
        }
    }
    __syncthreads();   // V consumed; reuse sB for z1r

    // ---- BN (fold b1) + ReLU -> sB[c][r] ----
    {
        const int c0 = tc * 4;
        float4 g  = *(const float4*)(gammaL + c0);
        float4 bt = *(const float4*)(betaL + c0);
        float4 mn = *(const float4*)(meanL + c0);
        float4 vv = *(const float4*)(varL + c0);
        float4 bb = *(const float4*)(b1L + c0);
        float sc[4], sh[4];
        sc[0] = g.x * rsqrtf(vv.x + EPS); sh[0] = (bb.x - mn.x) * sc[0] + bt.x;
        sc[1] = g.y * rsqrtf(vv.y + EPS); sh[1] = (bb.y - mn.y) * sc[1] + bt.y;
        sc[2] = g.z * rsqrtf(vv.z + EPS); sh[2] = (bb.z - mn.z) * sc[2] + bt.z;
        sc[3] = g.w * rsqrtf(vv.w + EPS); sh[3] = (bb.w - mn.w) * sc[3] + bt.w;
        #pragma unroll
        for (int j = 0; j < 4; ++j)
            #pragma unroll
            for (int i = 0; i < 4; ++i)
                sB[(c0 + j) * SV + tr * 4 + i] = fmaxf(acc[i][j] * sc[j] + sh[j], 0.f);
    }
    __syncthreads();

    // ---- Phase C: z2 = z1r @ W2 ; thread = 2 rows x 4 cols ----
    {
        const int tc2 = tid & 15, tr2 = tid >> 4;   // tc2: 0..15, tr2: 0..15
        const int c0 = tc2 * 4;
        float a2[2][4];
        #pragma unroll
        for (int i = 0; i < 2; ++i)
            #pragma unroll
            for (int j = 0; j < 4; ++j) a2[i][j] = 0.f;
        const float* wp = W2L + c0;
        #pragma unroll 4
        for (int k = 0; k < 128; ++k) {
            float4 w = *(const float4*)(wp + k * 64);
            float2 v = *(const float2*)(&sB[k * SV + tr2 * 2]);
            float wr[4] = {w.x, w.y, w.z, w.w};
            #pragma unroll
            for (int j = 0; j < 4; ++j) {
                a2[0][j] += v.x * wr[j];
                a2[1][j] += v.y * wr[j];
            }
        }
        float4 b2v = *(const float4*)(b2L + c0);
        float bb[4] = {b2v.x, b2v.y, b2v.z, b2v.w};
        #pragma unroll
        for (int i = 0; i < 2; ++i) {
            int n = n0 + tr2 * 2 + i;
            float4 o;
            o.x = a2[i][0] + bb[0];
            o.y = a2[i][1] + bb[1];
            o.z = a2[i][2] + bb[2];
            o.w = a2[i][3] + bb[3];
            if (relu_out) {
                o.x = fmaxf(o.x, 0.f); o.y = fmaxf(o.y, 0.f);
                o.z = fmaxf(o.z, 0.f); o.w = fmaxf(o.w, 0.f);
            }
            *(float4*)(h_out + n * H + c0) = o;
        }
    }
}

extern "C" void kernel_launch(void* const* d_in, const int* in_sizes, int n_in,
                              void* d_out, int out_size, void* d_ws, size_t ws_size,
                              hipStream_t stream) {
    const int*   x     = (const int*)d_in[0];
    const int*   ei    = (const int*)d_in[1];
    const float* eattr = (const float*)d_in[2];
    const float* emb0  = (const float*)d_in[3];
    const float* We    = (const float*)d_in[4];
    const float* be    = (const float*)d_in[5];
    const float* W1    = (const float*)d_in[6];
    const float* b1    = (const float*)d_in[7];
    const float* gamma = (const float*)d_in[8];
    const float* beta  = (const float*)d_in[9];
    const float* bnm   = (const float*)d_in[10];
    const float* bnv   = (const float*)d_in[11];
    const float* W2    = (const float*)d_in[12];
    const float* b2    = (const float*)d_in[13];
    const int*   slip  = (const int*)d_in[14];
    const int*   sltp  = (const int*)d_in[15];
    float* out = (float*)d_out;

    int*   deg    = (int*)d_ws + OFF_DEG;
    float* attr   = (float*)d_ws + OFF_ATTR;
    int*   rowptr = (int*)d_ws + OFF_ROWPTR;
    int*   cursor = (int*)d_ws + OFF_CURSOR;
    int*   pk     = (int*)d_ws + OFF_PK;
    float* h0     = (float*)d_ws + OFF_H0;
    float* h1     = (float*)d_ws + OFF_H1;

    hipMemsetAsync(d_ws, 0, (size_t)(N + N * EA) * 4, stream);

    k_count<<<dim3((E * 16 + 255) / 256), dim3(256), 0, stream>>>(ei, eattr, deg, attr);
    k_scan<<<dim3(1), dim3(1024), 0, stream>>>(deg, rowptr, cursor);
    k_fill<<<dim3((E + 255) / 256), dim3(256), 0, stream>>>(ei, cursor, pk);
    k_h0<<<dim3((N * H + 255) / 256), dim3(256), 0, stream>>>(x, emb0, h0);

    const int gblk = N / 4;    // 5000
    const int mblk = N / 32;   // 625

    // layer 0: h0 -> (agg=h1) -> h1
    k_gather<<<dim3(gblk), dim3(256), 0, stream>>>(h0, h1, rowptr, pk);
    k_mlp<<<dim3(mblk), dim3(256), 0, stream>>>(h1, h1, rowptr, attr,
        We + 0 * EA * H, be + 0 * H, W1 + 0 * 128 * 128, b1 + 0 * 128,
        gamma + 0 * 128, beta + 0 * 128, bnm + 0 * 128, bnv + 0 * 128,
        W2 + 0 * 128 * 64, b2 + 0 * 64, slip, sltp, 1);
    // layer 1: h1 -> (agg=h0) -> h0
    k_gather<<<dim3(gblk), dim3(256), 0, stream>>>(h1, h0, rowptr, pk);
    k_mlp<<<dim3(mblk), dim3(256), 0, stream>>>(h0, h0, rowptr, attr,
        We + 1 * EA * H, be + 1 * H, W1 + 1 * 128 * 128, b1 + 1 * 128,
        gamma + 1 * 128, beta + 1 * 128, bnm + 1 * 128, bnv + 1 * 128,
        W2 + 1 * 128 * 64, b2 + 1 * 64, slip, sltp, 1);
    // layer 2: h0 -> (agg=out) -> out (no final relu)
    k_gather<<<dim3(gblk), dim3(256), 0, stream>>>(h0, out, rowptr, pk);
    k_mlp<<<dim3(mblk), dim3(256), 0, stream>>>(out, out, rowptr, attr,
        We + 2 * EA * H, be + 2 * H, W1 + 2 * 128 * 128, b1 + 2 * 128,
        gamma + 2 * 128, beta + 2 * 128, bnm + 2 * 128, bnv + 2 * 128,
        W2 + 2 * 128 * 64, b2 + 2 * 64, slip, sltp, 0);
}

// Round 3
// 272.280 us; speedup vs baseline: 1.4554x; 1.1383x over previous
//
#include <hip/hip_runtime.h>
#include <hip/hip_bf16.h>

#define N   20000
#define E   320000
#define H   64
#define EA  9
#define EPS 1e-5f

#define SV  36     // LDS row stride in floats

// workspace element offsets (4B units)
#define OFF_DEG    0
#define OFF_CNT1   20000
#define OFF_ATTR   40000       // N*EA
#define OFF_ROWPTR 220000      // N+1 (+pad to 20016)
#define OFF_EPOS   240016      // E
#define OFF_PK     560016      // E
#define OFF_H0     880016      // N*H
#define OFF_H1     2160016     // N*H  -> end 3440016 elems = 13.76 MB

// 16 lanes per edge: q<9 attr atomics, q==9 deg count (+rank store), q==10 cnt1
__global__ void k_count(const int* __restrict__ ei, const float* __restrict__ eattr,
                        const int* __restrict__ x,
                        int* __restrict__ deg, int* __restrict__ cnt1,
                        float* __restrict__ attr, int* __restrict__ epos) {
    int t = blockIdx.x * 256 + threadIdx.x;
    int e = t >> 4, q = t & 15;
    if (e >= E) return;
    int s = ei[e];
    if (q < EA) {
        atomicAdd(&attr[s * EA + q], eattr[e * EA + q]);
    } else if (q == EA) {
        int r = atomicAdd(&deg[s], 1);
        epos[e] = r;
    } else if (q == 10) {
        int d = ei[E + e];
        atomicAdd(&cnt1[s], x[d]);
    }
}

// single block, 1024 threads, 20 elems/thread, int4-coalesced
__global__ void k_scan(const int* __restrict__ deg, int* __restrict__ rowptr) {
    __shared__ int wsum[16];
    const int tid = threadIdx.x, lane = tid & 63, w = tid >> 6;
    const int i0 = tid * 20;
    int loc[20];
    const int4* dv = (const int4*)(deg + i0);
    #pragma unroll
    for (int jj = 0; jj < 5; ++jj) {
        int4 v = dv[jj];
        int b = jj * 4;
        loc[b + 0] = (i0 + b + 0 < N) ? v.x : 0;
        loc[b + 1] = (i0 + b + 1 < N) ? v.y : 0;
        loc[b + 2] = (i0 + b + 2 < N) ? v.z : 0;
        loc[b + 3] = (i0 + b + 3 < N) ? v.w : 0;
    }
    int s = 0;
    #pragma unroll
    for (int j = 0; j < 20; ++j) s += loc[j];
    int t = s;
    #pragma unroll
    for (int off = 1; off < 64; off <<= 1) {
        int u = __shfl_up(t, off);
        if (lane >= off) t += u;
    }
    if (lane == 63) wsum[w] = t;
    __syncthreads();
    if (w == 0 && lane < 16) {
        int u = wsum[lane];
        #pragma unroll
        for (int off = 1; off < 16; off <<= 1) {
            int z = __shfl_up(u, off);
            if (lane >= off) u += z;
        }
        wsum[lane] = u;
    }
    __syncthreads();
    int excl = ((w == 0) ? 0 : wsum[w - 1]) + t - s;
    int o[20];
    #pragma unroll
    for (int j = 0; j < 20; ++j) { o[j] = excl; excl += loc[j]; }
    int4* rv = (int4*)(rowptr + i0);
    #pragma unroll
    for (int jj = 0; jj < 5; ++jj) {
        int b = jj * 4;
        if (i0 + b <= N)       // covers rowptr[N] via the first masked-tail thread
            rv[jj] = make_int4(o[b + 0], o[b + 1], o[b + 2], o[b + 3]);
    }
}

// atomic-free fill using precomputed per-edge rank
__global__ void k_fill(const int* __restrict__ ei, const int* __restrict__ rowptr,
                       const int* __restrict__ epos, int* __restrict__ pk) {
    int e = blockIdx.x * 256 + threadIdx.x;
    if (e >= E) return;
    int s = ei[e], d = ei[E + e];
    pk[rowptr[s] + epos[e]] = d;
}

// one wave per node: gather sum of neighbor h rows (+self) into aggH
__global__ __launch_bounds__(256, 8) void k_gather(
        const float* __restrict__ h_in, float* __restrict__ aggH,
        const int* __restrict__ rowptr, const int* __restrict__ pk) {
    const int lane = threadIdx.x & 63;
    const int n = blockIdx.x * 4 + (threadIdx.x >> 6);
    const int p0 = rowptr[n], p1 = rowptr[n + 1];
    float acc = h_in[n * H + lane];
    int p = p0;
    for (; p + 8 <= p1; p += 8) {
        int d0 = pk[p], d1 = pk[p + 1], d2 = pk[p + 2], d3 = pk[p + 3];
        int d4 = pk[p + 4], d5 = pk[p + 5], d6 = pk[p + 6], d7 = pk[p + 7];
        float v0 = h_in[d0 * H + lane];
        float v1 = h_in[d1 * H + lane];
        float v2 = h_in[d2 * H + lane];
        float v3 = h_in[d3 * H + lane];
        float v4 = h_in[d4 * H + lane];
        float v5 = h_in[d5 * H + lane];
        float v6 = h_in[d6 * H + lane];
        float v7 = h_in[d7 * H + lane];
        acc += v0; acc += v1; acc += v2; acc += v3;
        acc += v4; acc += v5; acc += v6; acc += v7;
    }
    for (; p < p1; ++p) acc += h_in[pk[p] * H + lane];
    aggH[n * H + lane] = acc;
}

// 32-row tile MLP. mode==0: layer-0, aggH synthesized from (cnt0,cnt1)x emb0.
// mode==1: load aggH rows (may alias h_out; block reads only its own rows).
__global__ __launch_bounds__(256, 4) void k_mlp(
        const float* __restrict__ aggH, float* __restrict__ h_out,
        const int* __restrict__ rowptr, const float* __restrict__ attr,
        const int* __restrict__ cnt1, const int* __restrict__ xarr,
        const float* __restrict__ emb0,
        const float* __restrict__ WeL, const float* __restrict__ beL,
        const float* __restrict__ W1L, const float* __restrict__ b1L,
        const float* __restrict__ gammaL, const float* __restrict__ betaL,
        const float* __restrict__ meanL, const float* __restrict__ varL,
        const float* __restrict__ W2L, const float* __restrict__ b2L,
        const int* __restrict__ slip, const int* __restrict__ sltp,
        int mode, int relu_out) {
    __shared__ float sB[128 * SV];   // 18432 B: V^T tile, then z1r tile
    const int tid = threadIdx.x;
    const int n0 = blockIdx.x * 32;

    // ---- Phase A: build V^T in LDS ----
    {
        const int r = tid >> 3, u = tid & 7;   // r: rows 0..31, u: 8-col groups
        const int n = n0 + r;
        const int dcnt_e = rowptr[n + 1] - rowptr[n];   // edge count (no self)
        float4 a0, a1;
        if (mode == 0) {
            int xv = xarr[n];
            int c1 = cnt1[n] + xv;
            int c0 = dcnt_e - cnt1[n] + (1 - xv);
            float f0 = (float)c0, f1 = (float)c1;
            float4 e0a = *(const float4*)(emb0 + u * 8);
            float4 e0b = *(const float4*)(emb0 + u * 8 + 4);
            float4 e1a = *(const float4*)(emb0 + H + u * 8);
            float4 e1b = *(const float4*)(emb0 + H + u * 8 + 4);
            a0.x = f0 * e0a.x + f1 * e1a.x; a0.y = f0 * e0a.y + f1 * e1a.y;
            a0.z = f0 * e0a.z + f1 * e1a.z; a0.w = f0 * e0a.w + f1 * e1a.w;
            a1.x = f0 * e0b.x + f1 * e1b.x; a1.y = f0 * e0b.y + f1 * e1b.y;
            a1.z = f0 * e0b.z + f1 * e1b.z; a1.w = f0 * e0b.w + f1 * e1b.w;
        } else {
            a0 = *(const float4*)(aggH + n * H + u * 8);
            a1 = *(const float4*)(aggH + n * H + u * 8 + 4);
        }
        sB[(u * 8 + 0) * SV + r] = a0.x;
        sB[(u * 8 + 1) * SV + r] = a0.y;
        sB[(u * 8 + 2) * SV + r] = a0.z;
        sB[(u * 8 + 3) * SV + r] = a0.w;
        sB[(u * 8 + 4) * SV + r] = a1.x;
        sB[(u * 8 + 5) * SV + r] = a1.y;
        sB[(u * 8 + 6) * SV + r] = a1.z;
        sB[(u * 8 + 7) * SV + r] = a1.w;
        // e-part: cols 64..127
        const int slidx = slip[0];
        const float slt = (float)sltp[0];
        float dcnt = (float)(dcnt_e + 1);
        float at[EA];
        #pragma unroll
        for (int j = 0; j < EA; ++j) at[j] = attr[n * EA + j];
        float4 v0, v1;
        {
            float4 s0 = *(const float4*)(WeL + slidx * H + u * 8);
            float4 s1 = *(const float4*)(WeL + slidx * H + u * 8 + 4);
            float4 e0 = *(const float4*)(beL + u * 8);
            float4 e1 = *(const float4*)(beL + u * 8 + 4);
            v0.x = slt * s0.x + dcnt * e0.x; v0.y = slt * s0.y + dcnt * e0.y;
            v0.z = slt * s0.z + dcnt * e0.z; v0.w = slt * s0.w + dcnt * e0.w;
            v1.x = slt * s1.x + dcnt * e1.x; v1.y = slt * s1.y + dcnt * e1.y;
            v1.z = slt * s1.z + dcnt * e1.z; v1.w = slt * s1.w + dcnt * e1.w;
        }
        #pragma unroll
        for (int k = 0; k < EA; ++k) {
            float4 w0 = *(const float4*)(WeL + k * H + u * 8);
            float4 w1 = *(const float4*)(WeL + k * H + u * 8 + 4);
            v0.x += at[k] * w0.x; v0.y += at[k] * w0.y;
            v0.z += at[k] * w0.z; v0.w += at[k] * w0.w;
            v1.x += at[k] * w1.x; v1.y += at[k] * w1.y;
            v1.z += at[k] * w1.z; v1.w += at[k] * w1.w;
        }
        sB[(H + u * 8 + 0) * SV + r] = v0.x;
        sB[(H + u * 8 + 1) * SV + r] = v0.y;
        sB[(H + u * 8 + 2) * SV + r] = v0.z;
        sB[(H + u * 8 + 3) * SV + r] = v0.w;
        sB[(H + u * 8 + 4) * SV + r] = v1.x;
        sB[(H + u * 8 + 5) * SV + r] = v1.y;
        sB[(H + u * 8 + 6) * SV + r] = v1.z;
        sB[(H + u * 8 + 7) * SV + r] = v1.w;
    }
    __syncthreads();

    // ---- Phase B: z1 = V @ W1 ; thread = 4 rows x 4 cols ----
    const int tc = tid & 31, tr = tid >> 5;
    float acc[4][4];
    #pragma unroll
    for (int i = 0; i < 4; ++i)
        #pragma unroll
        for (int j = 0; j < 4; ++j) acc[i][j] = 0.f;
    {
        const float* wp = W1L + tc * 4;
        #pragma unroll 4
        for (int k = 0; k < 128; ++k) {
            float4 w = *(const float4*)(wp + k * 128);
            float4 v = *(const float4*)(&sB[k * SV + tr * 4]);
            float wr[4] = {w.x, w.y, w.z, w.w};
            float vr[4] = {v.x, v.y, v.z, v.w};
            #pragma unroll
            for (int i = 0; i < 4; ++i)
                #pragma unroll
                for (int j = 0; j < 4; ++j) acc[i][j] += vr[i] * wr[j];
        }
    }
    __syncthreads();

    // ---- BN (fold b1) + ReLU -> sB[c][r] ----
    {
        const int c0 = tc * 4;
        float4 g  = *(const float4*)(gammaL + c0);
        float4 bt = *(const float4*)(betaL + c0);
        float4 mn = *(const float4*)(meanL + c0);
        float4 vv = *(const float4*)(varL + c0);
        float4 bb = *(const float4*)(b1L + c0);
        float sc[4], sh[4];
        sc[0] = g.x * rsqrtf(vv.x + EPS); sh[0] = (bb.x - mn.x) * sc[0] + bt.x;
        sc[1] = g.y * rsqrtf(vv.y + EPS); sh[1] = (bb.y - mn.y) * sc[1] + bt.y;
        sc[2] = g.z * rsqrtf(vv.z + EPS); sh[2] = (bb.z - mn.z) * sc[2] + bt.z;
        sc[3] = g.w * rsqrtf(vv.w + EPS); sh[3] = (bb.w - mn.w) * sc[3] + bt.w;
        #pragma unroll
        for (int j = 0; j < 4; ++j)
            #pragma unroll
            for (int i = 0; i < 4; ++i)
                sB[(c0 + j) * SV + tr * 4 + i] = fmaxf(acc[i][j] * sc[j] + sh[j], 0.f);
    }
    __syncthreads();

    // ---- Phase C: z2 = z1r @ W2 ; thread = 2 rows x 4 cols ----
    {
        const int tc2 = tid & 15, tr2 = tid >> 4;
        const int c0 = tc2 * 4;
        float a2[2][4];
        #pragma unroll
        for (int i = 0; i < 2; ++i)
            #pragma unroll
            for (int j = 0; j < 4; ++j) a2[i][j] = 0.f;
        const float* wp = W2L + c0;
        #pragma unroll 4
        for (int k = 0; k < 128; ++k) {
            float4 w = *(const float4*)(wp + k * 64);
            float2 v = *(const float2*)(&sB[k * SV + tr2 * 2]);
            float wr[4] = {w.x, w.y, w.z, w.w};
            #pragma unroll
            for (int j = 0; j < 4; ++j) {
                a2[0][j] += v.x * wr[j];
                a2[1][j] += v.y * wr[j];
            }
        }
        float4 b2v = *(const float4*)(b2L + c0);
        float bb[4] = {b2v.x, b2v.y, b2v.z, b2v.w};
        #pragma unroll
        for (int i = 0; i < 2; ++i) {
            int n = n0 + tr2 * 2 + i;
            float4 o;
            o.x = a2[i][0] + bb[0];
            o.y = a2[i][1] + bb[1];
            o.z = a2[i][2] + bb[2];
            o.w = a2[i][3] + bb[3];
            if (relu_out) {
                o.x = fmaxf(o.x, 0.f); o.y = fmaxf(o.y, 0.f);
                o.z = fmaxf(o.z, 0.f); o.w = fmaxf(o.w, 0.f);
            }
            *(float4*)(h_out + n * H + c0) = o;
        }
    }
}

extern "C" void kernel_launch(void* const* d_in, const int* in_sizes, int n_in,
                              void* d_out, int out_size, void* d_ws, size_t ws_size,
                              hipStream_t stream) {
    const int*   x     = (const int*)d_in[0];
    const int*   ei    = (const int*)d_in[1];
    const float* eattr = (const float*)d_in[2];
    const float* emb0  = (const float*)d_in[3];
    const float* We    = (const float*)d_in[4];
    const float* be    = (const float*)d_in[5];
    const float* W1    = (const float*)d_in[6];
    const float* b1    = (const float*)d_in[7];
    const float* gamma = (const float*)d_in[8];
    const float* beta  = (const float*)d_in[9];
    const float* bnm   = (const float*)d_in[10];
    const float* bnv   = (const float*)d_in[11];
    const float* W2    = (const float*)d_in[12];
    const float* b2    = (const float*)d_in[13];
    const int*   slip  = (const int*)d_in[14];
    const int*   sltp  = (const int*)d_in[15];
    float* out = (float*)d_out;

    int*   deg    = (int*)d_ws + OFF_DEG;
    int*   cnt1   = (int*)d_ws + OFF_CNT1;
    float* attr   = (float*)d_ws + OFF_ATTR;
    int*   rowptr = (int*)d_ws + OFF_ROWPTR;
    int*   epos   = (int*)d_ws + OFF_EPOS;
    int*   pk     = (int*)d_ws + OFF_PK;
    float* h0     = (float*)d_ws + OFF_H0;
    float* h1     = (float*)d_ws + OFF_H1;

    // zero deg + cnt1 + attr (contiguous 11N ints)
    hipMemsetAsync(d_ws, 0, (size_t)(2 * N + N * EA) * 4, stream);

    k_count<<<dim3((E * 16) / 256), dim3(256), 0, stream>>>(ei, eattr, x, deg, cnt1, attr, epos);
    k_scan<<<dim3(1), dim3(1024), 0, stream>>>(deg, rowptr);
    k_fill<<<dim3((E + 255) / 256), dim3(256), 0, stream>>>(ei, rowptr, epos, pk);

    const int gblk = N / 4;    // 5000
    const int mblk = N / 32;   // 625

    // layer 0: counts -> h1 (no gather needed)
    k_mlp<<<dim3(mblk), dim3(256), 0, stream>>>(h1, h1, rowptr, attr, cnt1, x, emb0,
        We + 0 * EA * H, be + 0 * H, W1 + 0 * 128 * 128, b1 + 0 * 128,
        gamma + 0 * 128, beta + 0 * 128, bnm + 0 * 128, bnv + 0 * 128,
        W2 + 0 * 128 * 64, b2 + 0 * 64, slip, sltp, 0, 1);
    // layer 1: h1 -> (agg=h0) -> h0
    k_gather<<<dim3(gblk), dim3(256), 0, stream>>>(h1, h0, rowptr, pk);
    k_mlp<<<dim3(mblk), dim3(256), 0, stream>>>(h0, h0, rowptr, attr, cnt1, x, emb0,
        We + 1 * EA * H, be + 1 * H, W1 + 1 * 128 * 128, b1 + 1 * 128,
        gamma + 1 * 128, beta + 1 * 128, bnm + 1 * 128, bnv + 1 * 128,
        W2 + 1 * 128 * 64, b2 + 1 * 64, slip, sltp, 1, 1);
    // layer 2: h0 -> (agg=out) -> out (no final relu)
    k_gather<<<dim3(gblk), dim3(256), 0, stream>>>(h0, out, rowptr, pk);
    k_mlp<<<dim3(mblk), dim3(256), 0, stream>>>(out, out, rowptr, attr, cnt1, x, emb0,
        We + 2 * EA * H, be + 2 * H, W1 + 2 * 128 * 128, b1 + 2 * 128,
        gamma + 2 * 128, beta + 2 * 128, bnm + 2 * 128, bnv + 2 * 128,
        W2 + 2 * 128 * 64, b2 + 2 * 64, slip, sltp, 1, 0);
}

// Round 4
// 250.077 us; speedup vs baseline: 1.5846x; 1.0888x over previous
//
#include <hip/hip_runtime.h>
#include <hip/hip_bf16.h>

#define N   20000
#define E   320000
#define H   64
#define EA  9
#define EPS 1e-5f

#define SV  36     // LDS row stride in floats

// workspace element offsets (4B units)
#define OFF_DEG    0
#define OFF_CNT1   20000
#define OFF_ATTR   40000       // N*EA -> 220000
#define OFF_ROWPTR 220000      // N+1 (+pad)
#define OFF_EPOS   240016      // E
#define OFF_PK2    560016      // E int2 (d, eid) -> 1200016
#define OFF_HB     1200016     // N*H bf16 (640000 u32) -> 1840016
#define OFF_AGG    1840016     // N*H f32 -> 3120016 elems = 12.48 MB

// one thread per edge: int atomics only (deg rank + cnt1)
__global__ void k_count(const int* __restrict__ ei, const int* __restrict__ x,
                        int* __restrict__ deg, int* __restrict__ cnt1,
                        int* __restrict__ epos) {
    int e = blockIdx.x * 256 + threadIdx.x;
    if (e >= E) return;
    int s = ei[e];
    epos[e] = atomicAdd(&deg[s], 1);
    int d = ei[E + e];
    int xv = x[d];
    if (xv) atomicAdd(&cnt1[s], xv);
}

// single block, 1024 threads, 20 elems/thread, int4-coalesced
__global__ void k_scan(const int* __restrict__ deg, int* __restrict__ rowptr) {
    __shared__ int wsum[16];
    const int tid = threadIdx.x, lane = tid & 63, w = tid >> 6;
    const int i0 = tid * 20;
    int loc[20];
    const int4* dv = (const int4*)(deg + i0);
    #pragma unroll
    for (int jj = 0; jj < 5; ++jj) {
        int4 v = dv[jj];
        int b = jj * 4;
        loc[b + 0] = (i0 + b + 0 < N) ? v.x : 0;
        loc[b + 1] = (i0 + b + 1 < N) ? v.y : 0;
        loc[b + 2] = (i0 + b + 2 < N) ? v.z : 0;
        loc[b + 3] = (i0 + b + 3 < N) ? v.w : 0;
    }
    int s = 0;
    #pragma unroll
    for (int j = 0; j < 20; ++j) s += loc[j];
    int t = s;
    #pragma unroll
    for (int off = 1; off < 64; off <<= 1) {
        int u = __shfl_up(t, off);
        if (lane >= off) t += u;
    }
    if (lane == 63) wsum[w] = t;
    __syncthreads();
    if (w == 0 && lane < 16) {
        int u = wsum[lane];
        #pragma unroll
        for (int off = 1; off < 16; off <<= 1) {
            int z = __shfl_up(u, off);
            if (lane >= off) u += z;
        }
        wsum[lane] = u;
    }
    __syncthreads();
    int excl = ((w == 0) ? 0 : wsum[w - 1]) + t - s;
    int o[20];
    #pragma unroll
    for (int j = 0; j < 20; ++j) { o[j] = excl; excl += loc[j]; }
    int4* rv = (int4*)(rowptr + i0);
    #pragma unroll
    for (int jj = 0; jj < 5; ++jj) {
        int b = jj * 4;
        if (i0 + b <= N)
            rv[jj] = make_int4(o[b + 0], o[b + 1], o[b + 2], o[b + 3]);
    }
}

// atomic-free fill: pk2[p] = (dst, eid)
__global__ void k_fill(const int* __restrict__ ei, const int* __restrict__ rowptr,
                       const int* __restrict__ epos, int2* __restrict__ pk2) {
    int e = blockIdx.x * 256 + threadIdx.x;
    if (e >= E) return;
    int s = ei[e], d = ei[E + e];
    pk2[rowptr[s] + epos[e]] = make_int2(d, e);
}

// 16 lanes per node, q<9 active: attr[n][q] = sum over CSR run of eattr[eid][q]
__global__ void k_attr(const float* __restrict__ eattr, const int* __restrict__ rowptr,
                       const int2* __restrict__ pk2, float* __restrict__ attr) {
    int t = blockIdx.x * 256 + threadIdx.x;
    int n = t >> 4, q = t & 15;
    if (n >= N || q >= EA) return;
    int p = rowptr[n], p1 = rowptr[n + 1];
    float s = 0.f;
    for (; p + 4 <= p1; p += 4) {
        int e0 = pk2[p].y, e1 = pk2[p + 1].y, e2 = pk2[p + 2].y, e3 = pk2[p + 3].y;
        float v0 = eattr[e0 * EA + q];
        float v1 = eattr[e1 * EA + q];
        float v2 = eattr[e2 * EA + q];
        float v3 = eattr[e3 * EA + q];
        s += v0; s += v1; s += v2; s += v3;
    }
    for (; p < p1; ++p) s += eattr[pk2[p].y * EA + q];
    attr[n * EA + q] = s;
}

// one wave per node: acc = self + sum neighbor rows (bf16 in, f32 acc/out)
__global__ __launch_bounds__(256, 8) void k_gather(
        const __hip_bfloat16* __restrict__ h_in, float* __restrict__ aggF,
        const int* __restrict__ rowptr, const int2* __restrict__ pk2) {
    const int lane = threadIdx.x & 63;
    const int n = blockIdx.x * 4 + (threadIdx.x >> 6);
    const int p0 = rowptr[n], p1 = rowptr[n + 1];
    float acc = __bfloat162float(h_in[n * H + lane]);
    int p = p0;
    for (; p + 8 <= p1; p += 8) {
        const int4* pv = (const int4*)(pk2 + p);
        int4 a = pv[0], b = pv[1], c = pv[2], d = pv[3];
        float v0 = __bfloat162float(h_in[a.x * H + lane]);
        float v1 = __bfloat162float(h_in[a.z * H + lane]);
        float v2 = __bfloat162float(h_in[b.x * H + lane]);
        float v3 = __bfloat162float(h_in[b.z * H + lane]);
        float v4 = __bfloat162float(h_in[c.x * H + lane]);
        float v5 = __bfloat162float(h_in[c.z * H + lane]);
        float v6 = __bfloat162float(h_in[d.x * H + lane]);
        float v7 = __bfloat162float(h_in[d.z * H + lane]);
        acc += v0; acc += v1; acc += v2; acc += v3;
        acc += v4; acc += v5; acc += v6; acc += v7;
    }
    for (; p < p1; ++p) acc += __bfloat162float(h_in[pk2[p].x * H + lane]);
    aggF[n * H + lane] = acc;
}

// 32-row tile MLP. mode==0: layer-0 agg synthesized from (cnt0,cnt1)x emb0 (exact).
// store_bf16: write h as bf16; else f32.
__global__ __launch_bounds__(256, 4) void k_mlp(
        const float* __restrict__ aggF, void* __restrict__ h_out,
        const int* __restrict__ rowptr, const float* __restrict__ attr,
        const int* __restrict__ cnt1, const int* __restrict__ xarr,
        const float* __restrict__ emb0,
        const float* __restrict__ WeL, const float* __restrict__ beL,
        const float* __restrict__ W1L, const float* __restrict__ b1L,
        const float* __restrict__ gammaL, const float* __restrict__ betaL,
        const float* __restrict__ meanL, const float* __restrict__ varL,
        const float* __restrict__ W2L, const float* __restrict__ b2L,
        const int* __restrict__ slip, const int* __restrict__ sltp,
        int mode, int relu_out, int store_bf16) {
    __shared__ float sB[128 * SV];   // 18432 B: V^T tile, then z1r tile
    const int tid = threadIdx.x;
    const int n0 = blockIdx.x * 32;

    // ---- Phase A: build V^T in LDS ----
    {
        const int r = tid >> 3, u = tid & 7;
        const int n = n0 + r;
        const int dcnt_e = rowptr[n + 1] - rowptr[n];
        float4 a0, a1;
        if (mode == 0) {
            int xv = xarr[n];
            int c1 = cnt1[n] + xv;
            int c0 = dcnt_e - cnt1[n] + (1 - xv);
            float f0 = (float)c0, f1 = (float)c1;
            float4 e0a = *(const float4*)(emb0 + u * 8);
            float4 e0b = *(const float4*)(emb0 + u * 8 + 4);
            float4 e1a = *(const float4*)(emb0 + H + u * 8);
            float4 e1b = *(const float4*)(emb0 + H + u * 8 + 4);
            a0.x = f0 * e0a.x + f1 * e1a.x; a0.y = f0 * e0a.y + f1 * e1a.y;
            a0.z = f0 * e0a.z + f1 * e1a.z; a0.w = f0 * e0a.w + f1 * e1a.w;
            a1.x = f0 * e0b.x + f1 * e1b.x; a1.y = f0 * e0b.y + f1 * e1b.y;
            a1.z = f0 * e0b.z + f1 * e1b.z; a1.w = f0 * e0b.w + f1 * e1b.w;
        } else {
            a0 = *(const float4*)(aggF + n * H + u * 8);
            a1 = *(const float4*)(aggF + n * H + u * 8 + 4);
        }
        sB[(u * 8 + 0) * SV + r] = a0.x;
        sB[(u * 8 + 1) * SV + r] = a0.y;
        sB[(u * 8 + 2) * SV + r] = a0.z;
        sB[(u * 8 + 3) * SV + r] = a0.w;
        sB[(u * 8 + 4) * SV + r] = a1.x;
        sB[(u * 8 + 5) * SV + r] = a1.y;
        sB[(u * 8 + 6) * SV + r] = a1.z;
        sB[(u * 8 + 7) * SV + r] = a1.w;
        // e-part: cols 64..127
        const int slidx = slip[0];
        const float slt = (float)sltp[0];
        float dcnt = (float)(dcnt_e + 1);
        float at[EA];
        #pragma unroll
        for (int j = 0; j < EA; ++j) at[j] = attr[n * EA + j];
        float4 v0, v1;
        {
            float4 s0 = *(const float4*)(WeL + slidx * H + u * 8);
            float4 s1 = *(const float4*)(WeL + slidx * H + u * 8 + 4);
            float4 e0 = *(const float4*)(beL + u * 8);
            float4 e1 = *(const float4*)(beL + u * 8 + 4);
            v0.x = slt * s0.x + dcnt * e0.x; v0.y = slt * s0.y + dcnt * e0.y;
            v0.z = slt * s0.z + dcnt * e0.z; v0.w = slt * s0.w + dcnt * e0.w;
            v1.x = slt * s1.x + dcnt * e1.x; v1.y = slt * s1.y + dcnt * e1.y;
            v1.z = slt * s1.z + dcnt * e1.z; v1.w = slt * s1.w + dcnt * e1.w;
        }
        #pragma unroll
        for (int k = 0; k < EA; ++k) {
            float4 w0 = *(const float4*)(WeL + k * H + u * 8);
            float4 w1 = *(const float4*)(WeL + k * H + u * 8 + 4);
            v0.x += at[k] * w0.x; v0.y += at[k] * w0.y;
            v0.z += at[k] * w0.z; v0.w += at[k] * w0.w;
            v1.x += at[k] * w1.x; v1.y += at[k] * w1.y;
            v1.z += at[k] * w1.z; v1.w += at[k] * w1.w;
        }
        sB[(H + u * 8 + 0) * SV + r] = v0.x;
        sB[(H + u * 8 + 1) * SV + r] = v0.y;
        sB[(H + u * 8 + 2) * SV + r] = v0.z;
        sB[(H + u * 8 + 3) * SV + r] = v0.w;
        sB[(H + u * 8 + 4) * SV + r] = v1.x;
        sB[(H + u * 8 + 5) * SV + r] = v1.y;
        sB[(H + u * 8 + 6) * SV + r] = v1.z;
        sB[(H + u * 8 + 7) * SV + r] = v1.w;
    }
    __syncthreads();

    // ---- Phase B: z1 = V @ W1 ; thread = 4 rows x 4 cols ----
    const int tc = tid & 31, tr = tid >> 5;
    float acc[4][4];
    #pragma unroll
    for (int i = 0; i < 4; ++i)
        #pragma unroll
        for (int j = 0; j < 4; ++j) acc[i][j] = 0.f;
    {
        const float* wp = W1L + tc * 4;
        #pragma unroll 4
        for (int k = 0; k < 128; ++k) {
            float4 w = *(const float4*)(wp + k * 128);
            float4 v = *(const float4*)(&sB[k * SV + tr * 4]);
            float wr[4] = {w.x, w.y, w.z, w.w};
            float vr[4] = {v.x, v.y, v.z, v.w};
            #pragma unroll
            for (int i = 0; i < 4; ++i)
                #pragma unroll
                for (int j = 0; j < 4; ++j) acc[i][j] += vr[i] * wr[j];
        }
    }
    __syncthreads();

    // ---- BN (fold b1) + ReLU -> sB[c][r] ----
    {
        const int c0 = tc * 4;
        float4 g  = *(const float4*)(gammaL + c0);
        float4 bt = *(const float4*)(betaL + c0);
        float4 mn = *(const float4*)(meanL + c0);
        float4 vv = *(const float4*)(varL + c0);
        float4 bb = *(const float4*)(b1L + c0);
        float sc[4], sh[4];
        sc[0] = g.x * rsqrtf(vv.x + EPS); sh[0] = (bb.x - mn.x) * sc[0] + bt.x;
        sc[1] = g.y * rsqrtf(vv.y + EPS); sh[1] = (bb.y - mn.y) * sc[1] + bt.y;
        sc[2] = g.z * rsqrtf(vv.z + EPS); sh[2] = (bb.z - mn.z) * sc[2] + bt.z;
        sc[3] = g.w * rsqrtf(vv.w + EPS); sh[3] = (bb.w - mn.w) * sc[3] + bt.w;
        #pragma unroll
        for (int j = 0; j < 4; ++j)
            #pragma unroll
            for (int i = 0; i < 4; ++i)
                sB[(c0 + j) * SV + tr * 4 + i] = fmaxf(acc[i][j] * sc[j] + sh[j], 0.f);
    }
    __syncthreads();

    // ---- Phase C: z2 = z1r @ W2 ; thread = 2 rows x 4 cols ----
    {
        const int tc2 = tid & 15, tr2 = tid >> 4;
        const int c0 = tc2 * 4;
        float a2[2][4];
        #pragma unroll
        for (int i = 0; i < 2; ++i)
            #pragma unroll
            for (int j = 0; j < 4; ++j) a2[i][j] = 0.f;
        const float* wp = W2L + c0;
        #pragma unroll 4
        for (int k = 0; k < 128; ++k) {
            float4 w = *(const float4*)(wp + k * 64);
            float2 v = *(const float2*)(&sB[k * SV + tr2 * 2]);
            float wr[4] = {w.x, w.y, w.z, w.w};
            #pragma unroll
            for (int j = 0; j < 4; ++j) {
                a2[0][j] += v.x * wr[j];
                a2[1][j] += v.y * wr[j];
            }
        }
        float4 b2v = *(const float4*)(b2L + c0);
        float bb[4] = {b2v.x, b2v.y, b2v.z, b2v.w};
        #pragma unroll
        for (int i = 0; i < 2; ++i) {
            int n = n0 + tr2 * 2 + i;
            float4 o;
            o.x = a2[i][0] + bb[0];
            o.y = a2[i][1] + bb[1];
            o.z = a2[i][2] + bb[2];
            o.w = a2[i][3] + bb[3];
            if (relu_out) {
                o.x = fmaxf(o.x, 0.f); o.y = fmaxf(o.y, 0.f);
                o.z = fmaxf(o.z, 0.f); o.w = fmaxf(o.w, 0.f);
            }
            if (store_bf16) {
                union { struct { __hip_bfloat162 a, b; } h; float2 f; } u;
                u.h.a = __float22bfloat162_rn(make_float2(o.x, o.y));
                u.h.b = __float22bfloat162_rn(make_float2(o.z, o.w));
                *(float2*)((__hip_bfloat16*)h_out + n * H + c0) = u.f;
            } else {
                *(float4*)((float*)h_out + n * H + c0) = o;
            }
        }
    }
}

extern "C" void kernel_launch(void* const* d_in, const int* in_sizes, int n_in,
                              void* d_out, int out_size, void* d_ws, size_t ws_size,
                              hipStream_t stream) {
    const int*   x     = (const int*)d_in[0];
    const int*   ei    = (const int*)d_in[1];
    const float* eattr = (const float*)d_in[2];
    const float* emb0  = (const float*)d_in[3];
    const float* We    = (const float*)d_in[4];
    const float* be    = (const float*)d_in[5];
    const float* W1    = (const float*)d_in[6];
    const float* b1    = (const float*)d_in[7];
    const float* gamma = (const float*)d_in[8];
    const float* beta  = (const float*)d_in[9];
    const float* bnm   = (const float*)d_in[10];
    const float* bnv   = (const float*)d_in[11];
    const float* W2    = (const float*)d_in[12];
    const float* b2    = (const float*)d_in[13];
    const int*   slip  = (const int*)d_in[14];
    const int*   sltp  = (const int*)d_in[15];
    float* out = (float*)d_out;

    int*   deg    = (int*)d_ws + OFF_DEG;
    int*   cnt1   = (int*)d_ws + OFF_CNT1;
    float* attr   = (float*)d_ws + OFF_ATTR;
    int*   rowptr = (int*)d_ws + OFF_ROWPTR;
    int*   epos   = (int*)d_ws + OFF_EPOS;
    int2*  pk2    = (int2*)((int*)d_ws + OFF_PK2);
    __hip_bfloat16* hb = (__hip_bfloat16*)((int*)d_ws + OFF_HB);
    float* aggF   = (float*)d_ws + OFF_AGG;

    // zero deg + cnt1 only (attr is written, not accumulated)
    hipMemsetAsync(d_ws, 0, (size_t)(2 * N) * 4, stream);

    k_count<<<dim3((E + 255) / 256), dim3(256), 0, stream>>>(ei, x, deg, cnt1, epos);
    k_scan<<<dim3(1), dim3(1024), 0, stream>>>(deg, rowptr);
    k_fill<<<dim3((E + 255) / 256), dim3(256), 0, stream>>>(ei, rowptr, epos, pk2);
    k_attr<<<dim3((N * 16 + 255) / 256), dim3(256), 0, stream>>>(eattr, rowptr, pk2, attr);

    const int gblk = N / 4;    // 5000
    const int mblk = N / 32;   // 625

    // layer 0: counts -> hb (bf16)
    k_mlp<<<dim3(mblk), dim3(256), 0, stream>>>(aggF, hb, rowptr, attr, cnt1, x, emb0,
        We + 0 * EA * H, be + 0 * H, W1 + 0 * 128 * 128, b1 + 0 * 128,
        gamma + 0 * 128, beta + 0 * 128, bnm + 0 * 128, bnv + 0 * 128,
        W2 + 0 * 128 * 64, b2 + 0 * 64, slip, sltp, 0, 1, 1);
    // layer 1: hb -> aggF -> hb
    k_gather<<<dim3(gblk), dim3(256), 0, stream>>>(hb, aggF, rowptr, pk2);
    k_mlp<<<dim3(mblk), dim3(256), 0, stream>>>(aggF, hb, rowptr, attr, cnt1, x, emb0,
        We + 1 * EA * H, be + 1 * H, W1 + 1 * 128 * 128, b1 + 1 * 128,
        gamma + 1 * 128, beta + 1 * 128, bnm + 1 * 128, bnv + 1 * 128,
        W2 + 1 * 128 * 64, b2 + 1 * 64, slip, sltp, 1, 1, 1);
    // layer 2: hb -> aggF -> out (f32, no final relu)
    k_gather<<<dim3(gblk), dim3(256), 0, stream>>>(hb, aggF, rowptr, pk2);
    k_mlp<<<dim3(mblk), dim3(256), 0, stream>>>(aggF, out, rowptr, attr, cnt1, x, emb0,
        We + 2 * EA * H, be + 2 * H, W1 + 2 * 128 * 128, b1 + 2 * 128,
        gamma + 2 * 128, beta + 2 * 128, bnm + 2 * 128, bnv + 2 * 128,
        W2 + 2 * 128 * 64, b2 + 2 * 64, slip, sltp, 1, 0, 0);
}